// Round 1
// baseline (220.381 us; speedup 1.0000x reference)
//
#include <hip/hip_runtime.h>
#include <math.h>

#define NROWS 8192
#define HALF  4096
#define EMB   2048
#define DIM   256
#define INV_T 10.0f

typedef __bf16 bf16x8v __attribute__((ext_vector_type(8)));
typedef __bf16 bf16x4v __attribute__((ext_vector_type(4)));
typedef float  f32x4   __attribute__((ext_vector_type(4)));

__device__ __forceinline__ void gld_lds16(const void* g, void* l) {
    __builtin_amdgcn_global_load_lds((const __attribute__((address_space(1))) void*)g,
                                     (__attribute__((address_space(3))) void*)l,
                                     16, 0, 0);
}

// ---------- K0: W [2048][256] f32 -> Wt [256][2048] bf16 (transpose+convert) ----------
__global__ __launch_bounds__(256) void wt_kernel(const float* __restrict__ W,
                                                 __bf16* __restrict__ Wt) {
    int idx = blockIdx.x * 256 + threadIdx.x;   // 0 .. 256*2048-1
    int n = idx >> 11;                          // output row (0..255)
    int k = idx & 2047;                         // output col (0..2047)
    Wt[idx] = (__bf16)W[k * DIM + n];
}

// ---------- K1: out_head = emb@W + b, L2-normalize rows, write bf16 X ----------
#define K1_ROWS 32
#define K1_BK   32

__global__ __launch_bounds__(256) void gemm_norm_kernel(
    const float* __restrict__ A,      // [8192][2048] f32
    const __bf16* __restrict__ Wt,    // [256][2048] bf16 (W transposed)
    const float* __restrict__ bias,   // [256]
    __bf16* __restrict__ outb)        // [8192][256] bf16 normalized
{
    __shared__ __bf16 a_sh[K1_ROWS][K1_BK];   // 2 KB
    __shared__ __bf16 b_sh[DIM][K1_BK];       // 16 KB (reused as store-staging)
    __shared__ float norm2[K1_ROWS];

    const int tid  = threadIdx.x;
    const int wave = tid >> 6, lane = tid & 63;
    const int quad = lane >> 4, l15 = lane & 15;
    const int rowBase = blockIdx.x * K1_ROWS;
    const int waveRow = (wave >> 1) * 16;   // 0 or 16
    const int waveCol = (wave & 1) * 128;   // 0 or 128

    f32x4 acc[8];
    const f32x4 zero = {0.f, 0.f, 0.f, 0.f};
#pragma unroll
    for (int s = 0; s < 8; s++) acc[s] = zero;

    const int ar = tid >> 3;            // 0..31 row for A staging
    const int ac = (tid & 7) * 4;       // 0..28 col chunk
    const float* aptr = A + (size_t)(rowBase + ar) * EMB + ac;

    float4 a_cur = *(const float4*)aptr;   // prefetch k0=0 chunk

    for (int k0 = 0; k0 < EMB; k0 += K1_BK) {
        __syncthreads();
        // stage A: convert fp32 -> bf16, ds_write
        bf16x4v av;
        av[0] = (__bf16)a_cur.x; av[1] = (__bf16)a_cur.y;
        av[2] = (__bf16)a_cur.z; av[3] = (__bf16)a_cur.w;
        *(bf16x4v*)&a_sh[ar][ac] = av;
        // stage B (already bf16): 16 KB = 16 segs of 1KB, 4 per wave
#pragma unroll
        for (int j = 0; j < 4; j++) {
            int seg = wave * 4 + j;
            int n = seg * 16 + (lane >> 2);
            int kloc = (lane & 3) * 8;
            gld_lds16(Wt + (size_t)n * EMB + k0 + kloc, (__bf16*)b_sh + seg * 512);
        }
        // prefetch next A chunk (hides HBM latency across the barrier drain)
        if (k0 + K1_BK < EMB) a_cur = *(const float4*)(aptr + k0 + K1_BK);
        __syncthreads();
        // compute: 1 A-frag, 8 B-frags, 8 MFMA per wave
        bf16x8v af = *(const bf16x8v*)&a_sh[waveRow + l15][quad * 8];
#pragma unroll
        for (int s = 0; s < 8; s++) {
            bf16x8v bfv = *(const bf16x8v*)&b_sh[waveCol + s * 16 + l15][quad * 8];
            acc[s] = __builtin_amdgcn_mfma_f32_16x16x32_bf16(af, bfv, acc[s], 0, 0, 0);
        }
    }

    __syncthreads();
    if (tid < K1_ROWS) norm2[tid] = 0.f;
    __syncthreads();

    float bv[8];
#pragma unroll
    for (int s = 0; s < 8; s++) bv[s] = bias[waveCol + s * 16 + l15];

    // C/D layout: col = lane&15, row = quad*4 + reg  (m89/m91 verified)
    float vals[8][4];
    float ss[4] = {0.f, 0.f, 0.f, 0.f};
#pragma unroll
    for (int s = 0; s < 8; s++)
#pragma unroll
        for (int r = 0; r < 4; r++) {
            float v = acc[s][r] + bv[s];
            vals[s][r] = v;
            ss[r] += v * v;
        }
#pragma unroll
    for (int off = 1; off < 16; off <<= 1)
#pragma unroll
        for (int r = 0; r < 4; r++) ss[r] += __shfl_xor(ss[r], off, 64);
    if (l15 == 0)
#pragma unroll
        for (int r = 0; r < 4; r++) atomicAdd(&norm2[waveRow + quad * 4 + r], ss[r]);
    __syncthreads();

    float inv[4];
#pragma unroll
    for (int r = 0; r < 4; r++)
        inv[r] = 1.f / fmaxf(sqrtf(norm2[waveRow + quad * 4 + r]), 1e-12f);

    // write normalized bf16 tile through LDS (reuse b_sh) for coalesced stores
    __bf16* c_sh = &b_sh[0][0];   // 32*256 = 8192 elements = 16 KB, fits exactly
#pragma unroll
    for (int s = 0; s < 8; s++)
#pragma unroll
        for (int r = 0; r < 4; r++)
            c_sh[(waveRow + quad * 4 + r) * DIM + waveCol + s * 16 + l15] =
                (__bf16)(vals[s][r] * inv[r]);
    __syncthreads();

    const int4* src = (const int4*)c_sh;
    int4* dst = (int4*)(outb + (size_t)rowBase * DIM);
#pragma unroll
    for (int it = 0; it < 4; it++) dst[it * 256 + tid] = src[it * 256 + tid];
}

// ---------- K2: sim = X@X^T fused exp/mask/rowsum + pos capture ----------
#define TILE 128
#define BK2  32

__global__ __launch_bounds__(256) void sim_kernel(
    const __bf16* __restrict__ X,   // [8192][256] normalized bf16
    float* __restrict__ total,      // [8192] pre-zeroed, atomic accum of neg sums
    float* __restrict__ posv)       // [8192] raw partner dot per row
{
    __shared__ __bf16 a_sh[TILE][BK2];   // 8 KB
    __shared__ __bf16 b_sh[TILE][BK2];   // 8 KB
    __shared__ float rowsum[TILE];

    const int tid  = threadIdx.x;
    const int wave = tid >> 6, lane = tid & 63;
    const int quad = lane >> 4, l15 = lane & 15;
    const int rowBase = blockIdx.x * TILE;
    const int colBase = blockIdx.y * TILE;
    const int waveRow = (wave >> 1) * 64;
    const int waveCol = (wave & 1) * 64;

    f32x4 acc[4][4];
    const f32x4 zero = {0.f, 0.f, 0.f, 0.f};
#pragma unroll
    for (int m = 0; m < 4; m++)
#pragma unroll
        for (int n = 0; n < 4; n++) acc[m][n] = zero;

    if (tid < TILE) rowsum[tid] = 0.f;

    const int sr   = lane >> 2;        // sub-row within 16-row segment
    const int kloc = (lane & 3) * 8;

    for (int k0 = 0; k0 < DIM; k0 += BK2) {
        __syncthreads();
        // stage A rows (rowBase) and B rows (colBase); both K-contiguous (A·A^T)
#pragma unroll
        for (int j = 0; j < 2; j++) {
            int seg = wave * 2 + j;
            int r = seg * 16 + sr;
            gld_lds16(X + (size_t)(rowBase + r) * DIM + k0 + kloc, (__bf16*)a_sh + seg * 512);
            gld_lds16(X + (size_t)(colBase + r) * DIM + k0 + kloc, (__bf16*)b_sh + seg * 512);
        }
        __syncthreads();
        bf16x8v af[4], bfv[4];
#pragma unroll
        for (int m = 0; m < 4; m++)
            af[m] = *(const bf16x8v*)&a_sh[waveRow + m * 16 + l15][quad * 8];
#pragma unroll
        for (int n = 0; n < 4; n++)
            bfv[n] = *(const bf16x8v*)&b_sh[waveCol + n * 16 + l15][quad * 8];
#pragma unroll
        for (int m = 0; m < 4; m++)
#pragma unroll
            for (int n = 0; n < 4; n++)
                acc[m][n] = __builtin_amdgcn_mfma_f32_16x16x32_bf16(af[m], bfv[n], acc[m][n], 0, 0, 0);
    }

    // epilogue: exp, diag mask, partner capture, row-sum
#pragma unroll
    for (int m = 0; m < 4; m++) {
#pragma unroll
        for (int r = 0; r < 4; r++) {
            int lrow = waveRow + m * 16 + quad * 4 + r;
            int grow = rowBase + lrow;
            float es = 0.f;
#pragma unroll
            for (int n = 0; n < 4; n++) {
                int gcol = colBase + waveCol + n * 16 + l15;
                float s = acc[m][n][r];
                if (gcol - grow == HALF || grow - gcol == HALF) posv[grow] = s;
                es += (gcol == grow) ? 0.f : __expf(s * INV_T);
            }
#pragma unroll
            for (int off = 1; off < 16; off <<= 1) es += __shfl_xor(es, off, 64);
            if (l15 == 0) atomicAdd(&rowsum[lrow], es);
        }
    }
    __syncthreads();
    if (tid < TILE) atomicAdd(&total[rowBase + tid], rowsum[tid]);
}

// ---------- K3: loss = -(1/n) sum(pos/T - log(neg)) ----------
__global__ __launch_bounds__(1024) void loss_kernel(
    const float* __restrict__ total, const float* __restrict__ posv,
    float* __restrict__ out)
{
    __shared__ float red[16];
    int tid = threadIdx.x;
    float s = 0.f;
    for (int i = tid; i < NROWS; i += 1024)
        s += posv[i] * INV_T - __logf(total[i]);
#pragma unroll
    for (int off = 32; off > 0; off >>= 1) s += __shfl_down(s, off, 64);
    if ((tid & 63) == 0) red[tid >> 6] = s;
    __syncthreads();
    if (tid < 16) {
        float v = red[tid];
#pragma unroll
        for (int off = 8; off > 0; off >>= 1) v += __shfl_down(v, off, 64);
        if (tid == 0) out[0] = -v / (float)NROWS;
    }
}

extern "C" void kernel_launch(void* const* d_in, const int* in_sizes, int n_in,
                              void* d_out, int out_size, void* d_ws, size_t ws_size,
                              hipStream_t stream) {
    const float* emb  = (const float*)d_in[0];   // [8192*2048] f32
    const float* W    = (const float*)d_in[1];   // [2048*256] f32
    const float* bias = (const float*)d_in[2];   // [256] f32
    float* out = (float*)d_out;                  // scalar f32

    char* ws = (char*)d_ws;
    __bf16* outb = (__bf16*)ws;                              // 4 MB normalized X
    __bf16* Wt   = (__bf16*)(ws + (4u << 20));               // 1 MB W^T bf16
    float* total = (float*)(ws + (5u << 20));                // 32 KB neg sums
    float* posv  = (float*)(ws + (5u << 20) + (32u << 10));  // 32 KB partner dots

    hipMemsetAsync(total, 0, NROWS * sizeof(float), stream);
    wt_kernel<<<dim3((EMB * DIM) / 256), 256, 0, stream>>>(W, Wt);
    gemm_norm_kernel<<<dim3(NROWS / K1_ROWS), 256, 0, stream>>>(emb, Wt, bias, outb);
    sim_kernel<<<dim3(NROWS / TILE, NROWS / TILE), 256, 0, stream>>>(outb, total, posv);
    loss_kernel<<<dim3(1), 1024, 0, stream>>>(total, posv, out);
}

// Round 2
// 207.685 us; speedup vs baseline: 1.0611x; 1.0611x over previous
//
#include <hip/hip_runtime.h>
#include <math.h>

#define NROWS 8192
#define HALF  4096
#define EMB   2048
#define DIM   256
#define INV_T 10.0f

typedef __bf16 bf16x8v __attribute__((ext_vector_type(8)));
typedef __bf16 bf16x4v __attribute__((ext_vector_type(4)));
typedef float  f32x4   __attribute__((ext_vector_type(4)));

__device__ __forceinline__ void gld_lds16(const void* g, void* l) {
    __builtin_amdgcn_global_load_lds((const __attribute__((address_space(1))) void*)g,
                                     (__attribute__((address_space(3))) void*)l,
                                     16, 0, 0);
}

// ---------- K0: W [2048][256] f32 -> Wt [256][2048] bf16, coalesced tile transpose ----------
// tile: 64 k x 64 n. grid (256/64, 2048/64) = (4, 32), 256 threads.
__global__ __launch_bounds__(256) void wt_kernel(const float* __restrict__ W,
                                                 __bf16* __restrict__ Wt) {
    __shared__ __bf16 t[64][72];   // [k][n], pad 64->72 to break write conflicts
    const int n0 = blockIdx.x * 64;
    const int k0 = blockIdx.y * 64;
    const int tid = threadIdx.x;
    const int c = tid & 63;       // 0..63
    const int rr = tid >> 6;      // 0..3
#pragma unroll
    for (int it = 0; it < 16; it++) {
        int k = it * 4 + rr;
        t[k][c] = (__bf16)W[(size_t)(k0 + k) * DIM + n0 + c];   // coalesced read (256B/row)
    }
    __syncthreads();
#pragma unroll
    for (int it = 0; it < 16; it++) {
        int n = it * 4 + rr;
        Wt[(size_t)(n0 + n) * EMB + k0 + c] = t[c][n];          // coalesced write (128B/row)
    }
}

// ---------- K1a: partial GEMM, K split 4 ways. grid (256, 4) ----------
#define K1_ROWS 32
#define K1_BK   32
#define KSPLIT  4
#define KCHUNK  (EMB / KSPLIT)   // 512

__global__ __launch_bounds__(256) void gemm_part_kernel(
    const float* __restrict__ A,      // [8192][2048] f32
    const __bf16* __restrict__ Wt,    // [256][2048] bf16
    float* __restrict__ parts)        // [4][8192][256] f32
{
    __shared__ __bf16 a_sh[K1_ROWS][K1_BK];   // 2 KB
    __shared__ __bf16 b_sh[DIM][K1_BK];       // 16 KB

    const int tid  = threadIdx.x;
    const int wave = tid >> 6, lane = tid & 63;
    const int quad = lane >> 4, l15 = lane & 15;
    const int rowBase = blockIdx.x * K1_ROWS;
    const int kOff    = blockIdx.y * KCHUNK;
    const int waveRow = (wave >> 1) * 16;
    const int waveCol = (wave & 1) * 128;

    f32x4 acc[8];
    const f32x4 zero = {0.f, 0.f, 0.f, 0.f};
#pragma unroll
    for (int s = 0; s < 8; s++) acc[s] = zero;

    const int ar = tid >> 3;
    const int ac = (tid & 7) * 4;
    const float* aptr = A + (size_t)(rowBase + ar) * EMB + kOff + ac;
    float4 a_cur = *(const float4*)aptr;

    for (int k0 = 0; k0 < KCHUNK; k0 += K1_BK) {
        __syncthreads();
        bf16x4v av;
        av[0] = (__bf16)a_cur.x; av[1] = (__bf16)a_cur.y;
        av[2] = (__bf16)a_cur.z; av[3] = (__bf16)a_cur.w;
        *(bf16x4v*)&a_sh[ar][ac] = av;
#pragma unroll
        for (int j = 0; j < 4; j++) {
            int seg = wave * 4 + j;
            int n = seg * 16 + (lane >> 2);
            int kloc = (lane & 3) * 8;
            gld_lds16(Wt + (size_t)n * EMB + kOff + k0 + kloc, (__bf16*)b_sh + seg * 512);
        }
        if (k0 + K1_BK < KCHUNK) a_cur = *(const float4*)(aptr + k0 + K1_BK);
        __syncthreads();
        bf16x8v af = *(const bf16x8v*)&a_sh[waveRow + l15][quad * 8];
#pragma unroll
        for (int s = 0; s < 8; s++) {
            bf16x8v bfv = *(const bf16x8v*)&b_sh[waveCol + s * 16 + l15][quad * 8];
            acc[s] = __builtin_amdgcn_mfma_f32_16x16x32_bf16(af, bfv, acc[s], 0, 0, 0);
        }
    }

    float* p = parts + (size_t)blockIdx.y * NROWS * DIM;
    // C/D layout: col = lane&15, row = quad*4 + reg
#pragma unroll
    for (int s = 0; s < 8; s++)
#pragma unroll
        for (int r = 0; r < 4; r++)
            p[(size_t)(rowBase + waveRow + quad * 4 + r) * DIM + waveCol + s * 16 + l15] =
                acc[s][r];
}

// ---------- K1b: sum partials + bias, L2-normalize, emit bf16 X. grid 2048 ----------
__global__ __launch_bounds__(256) void norm_kernel(
    const float* __restrict__ parts,
    const float* __restrict__ bias,
    __bf16* __restrict__ outb)
{
    const int tid  = threadIdx.x;
    const int wave = tid >> 6, lane = tid & 63;
    const int row  = blockIdx.x * 4 + wave;

    float4 v = {0.f, 0.f, 0.f, 0.f};
#pragma unroll
    for (int kc = 0; kc < KSPLIT; kc++) {
        float4 pv = *(const float4*)(parts + (size_t)kc * NROWS * DIM + (size_t)row * DIM + lane * 4);
        v.x += pv.x; v.y += pv.y; v.z += pv.z; v.w += pv.w;
    }
    float4 bv = ((const float4*)bias)[lane];
    v.x += bv.x; v.y += bv.y; v.z += bv.z; v.w += bv.w;

    float ss = v.x * v.x + v.y * v.y + v.z * v.z + v.w * v.w;
#pragma unroll
    for (int off = 1; off < 64; off <<= 1) ss += __shfl_xor(ss, off, 64);
    float inv = 1.f / fmaxf(sqrtf(ss), 1e-12f);

    bf16x4v o;
    o[0] = (__bf16)(v.x * inv); o[1] = (__bf16)(v.y * inv);
    o[2] = (__bf16)(v.z * inv); o[3] = (__bf16)(v.w * inv);
    *(bf16x4v*)(outb + (size_t)row * DIM + lane * 4) = o;
}

// ---------- K1 fallback (single kernel, used if ws too small for partials) ----------
__global__ __launch_bounds__(256) void gemm_norm_kernel(
    const float* __restrict__ A, const __bf16* __restrict__ Wt,
    const float* __restrict__ bias, __bf16* __restrict__ outb)
{
    __shared__ __bf16 a_sh[K1_ROWS][K1_BK];
    __shared__ __bf16 b_sh[DIM][K1_BK];
    __shared__ float norm2[K1_ROWS];

    const int tid  = threadIdx.x;
    const int wave = tid >> 6, lane = tid & 63;
    const int quad = lane >> 4, l15 = lane & 15;
    const int rowBase = blockIdx.x * K1_ROWS;
    const int waveRow = (wave >> 1) * 16;
    const int waveCol = (wave & 1) * 128;

    f32x4 acc[8];
    const f32x4 zero = {0.f, 0.f, 0.f, 0.f};
#pragma unroll
    for (int s = 0; s < 8; s++) acc[s] = zero;

    const int ar = tid >> 3;
    const int ac = (tid & 7) * 4;
    const float* aptr = A + (size_t)(rowBase + ar) * EMB + ac;
    float4 a_cur = *(const float4*)aptr;

    for (int k0 = 0; k0 < EMB; k0 += K1_BK) {
        __syncthreads();
        bf16x4v av;
        av[0] = (__bf16)a_cur.x; av[1] = (__bf16)a_cur.y;
        av[2] = (__bf16)a_cur.z; av[3] = (__bf16)a_cur.w;
        *(bf16x4v*)&a_sh[ar][ac] = av;
#pragma unroll
        for (int j = 0; j < 4; j++) {
            int seg = wave * 4 + j;
            int n = seg * 16 + (lane >> 2);
            int kloc = (lane & 3) * 8;
            gld_lds16(Wt + (size_t)n * EMB + k0 + kloc, (__bf16*)b_sh + seg * 512);
        }
        if (k0 + K1_BK < EMB) a_cur = *(const float4*)(aptr + k0 + K1_BK);
        __syncthreads();
        bf16x8v af = *(const bf16x8v*)&a_sh[waveRow + l15][quad * 8];
#pragma unroll
        for (int s = 0; s < 8; s++) {
            bf16x8v bfv = *(const bf16x8v*)&b_sh[waveCol + s * 16 + l15][quad * 8];
            acc[s] = __builtin_amdgcn_mfma_f32_16x16x32_bf16(af, bfv, acc[s], 0, 0, 0);
        }
    }

    __syncthreads();
    if (tid < K1_ROWS) norm2[tid] = 0.f;
    __syncthreads();

    float bv[8];
#pragma unroll
    for (int s = 0; s < 8; s++) bv[s] = bias[waveCol + s * 16 + l15];

    float vals[8][4];
    float ss[4] = {0.f, 0.f, 0.f, 0.f};
#pragma unroll
    for (int s = 0; s < 8; s++)
#pragma unroll
        for (int r = 0; r < 4; r++) {
            float v = acc[s][r] + bv[s];
            vals[s][r] = v;
            ss[r] += v * v;
        }
#pragma unroll
    for (int off = 1; off < 16; off <<= 1)
#pragma unroll
        for (int r = 0; r < 4; r++) ss[r] += __shfl_xor(ss[r], off, 64);
    if (l15 == 0)
#pragma unroll
        for (int r = 0; r < 4; r++) atomicAdd(&norm2[waveRow + quad * 4 + r], ss[r]);
    __syncthreads();

    float inv[4];
#pragma unroll
    for (int r = 0; r < 4; r++)
        inv[r] = 1.f / fmaxf(sqrtf(norm2[waveRow + quad * 4 + r]), 1e-12f);

    __bf16* c_sh = &b_sh[0][0];
#pragma unroll
    for (int s = 0; s < 8; s++)
#pragma unroll
        for (int r = 0; r < 4; r++)
            c_sh[(waveRow + quad * 4 + r) * DIM + waveCol + s * 16 + l15] =
                (__bf16)(vals[s][r] * inv[r]);
    __syncthreads();

    const int4* src = (const int4*)c_sh;
    int4* dst = (int4*)(outb + (size_t)rowBase * DIM);
#pragma unroll
    for (int it = 0; it < 4; it++) dst[it * 256 + tid] = src[it * 256 + tid];
}

// ---------- K2: upper-triangle tiles only; row-sums + col-sums via symmetry ----------
#define TILE 128
#define BK2  32

__global__ __launch_bounds__(256) void sim_kernel(
    const __bf16* __restrict__ X,
    float* __restrict__ total,
    float* __restrict__ posv)
{
    const int bx = blockIdx.x;   // row tile
    const int by = blockIdx.y;   // col tile
    if (by < bx) return;         // symmetry: upper triangle only
    const bool diag = (bx == by);

    __shared__ __bf16 a_sh[TILE][BK2];
    __shared__ __bf16 b_sh[TILE][BK2];
    __shared__ float rowsum[TILE];
    __shared__ float colsum[TILE];

    const int tid  = threadIdx.x;
    const int wave = tid >> 6, lane = tid & 63;
    const int quad = lane >> 4, l15 = lane & 15;
    const int rowBase = bx * TILE;
    const int colBase = by * TILE;
    const int waveRow = (wave >> 1) * 64;
    const int waveCol = (wave & 1) * 64;

    f32x4 acc[4][4];
    const f32x4 zero = {0.f, 0.f, 0.f, 0.f};
#pragma unroll
    for (int m = 0; m < 4; m++)
#pragma unroll
        for (int n = 0; n < 4; n++) acc[m][n] = zero;

    if (tid < TILE) { rowsum[tid] = 0.f; colsum[tid] = 0.f; }

    const int sr   = lane >> 2;
    const int kloc = (lane & 3) * 8;

    for (int k0 = 0; k0 < DIM; k0 += BK2) {
        __syncthreads();
#pragma unroll
        for (int j = 0; j < 2; j++) {
            int seg = wave * 2 + j;
            int r = seg * 16 + sr;
            gld_lds16(X + (size_t)(rowBase + r) * DIM + k0 + kloc, (__bf16*)a_sh + seg * 512);
            gld_lds16(X + (size_t)(colBase + r) * DIM + k0 + kloc, (__bf16*)b_sh + seg * 512);
        }
        __syncthreads();
        bf16x8v af[4], bfv[4];
#pragma unroll
        for (int m = 0; m < 4; m++)
            af[m] = *(const bf16x8v*)&a_sh[waveRow + m * 16 + l15][quad * 8];
#pragma unroll
        for (int n = 0; n < 4; n++)
            bfv[n] = *(const bf16x8v*)&b_sh[waveCol + n * 16 + l15][quad * 8];
#pragma unroll
        for (int m = 0; m < 4; m++)
#pragma unroll
            for (int n = 0; n < 4; n++)
                acc[m][n] = __builtin_amdgcn_mfma_f32_16x16x32_bf16(af[m], bfv[n], acc[m][n], 0, 0, 0);
    }

    // epilogue
    float ecol[4] = {0.f, 0.f, 0.f, 0.f};
#pragma unroll
    for (int m = 0; m < 4; m++) {
#pragma unroll
        for (int r = 0; r < 4; r++) {
            int lrow = waveRow + m * 16 + quad * 4 + r;
            int grow = rowBase + lrow;
            float es = 0.f;
#pragma unroll
            for (int n = 0; n < 4; n++) {
                int gcol = colBase + waveCol + n * 16 + l15;
                float s = acc[m][n][r];
                if (gcol - grow == HALF) { posv[grow] = s; posv[gcol] = s; }
                float e = (gcol == grow) ? 0.f : __expf(s * INV_T);
                es += e;
                ecol[n] += e;
            }
#pragma unroll
            for (int off = 1; off < 16; off <<= 1) es += __shfl_xor(es, off, 64);
            if (l15 == 0) atomicAdd(&rowsum[lrow], es);
        }
    }
    if (!diag) {
#pragma unroll
        for (int n = 0; n < 4; n++) {
            ecol[n] += __shfl_xor(ecol[n], 16, 64);
            ecol[n] += __shfl_xor(ecol[n], 32, 64);
        }
        if (quad == 0)
#pragma unroll
            for (int n = 0; n < 4; n++)
                atomicAdd(&colsum[waveCol + n * 16 + l15], ecol[n]);
    }
    __syncthreads();
    if (tid < TILE) {
        atomicAdd(&total[rowBase + tid], rowsum[tid]);
        if (!diag) atomicAdd(&total[colBase + tid], colsum[tid]);
    }
}

// ---------- K3: loss ----------
__global__ __launch_bounds__(256) void loss_kernel(
    const float* __restrict__ total, const float* __restrict__ posv,
    float* __restrict__ out)
{
    __shared__ float red[4];
    const int tid = threadIdx.x;
    const int i = blockIdx.x * 256 + tid;
    float s = posv[i] * INV_T - __logf(total[i]);
#pragma unroll
    for (int off = 1; off < 64; off <<= 1) s += __shfl_xor(s, off, 64);
    if ((tid & 63) == 0) red[tid >> 6] = s;
    __syncthreads();
    if (tid == 0) {
        float v = red[0] + red[1] + red[2] + red[3];
        atomicAdd(out, -v / (float)NROWS);
    }
}

extern "C" void kernel_launch(void* const* d_in, const int* in_sizes, int n_in,
                              void* d_out, int out_size, void* d_ws, size_t ws_size,
                              hipStream_t stream) {
    const float* emb  = (const float*)d_in[0];
    const float* W    = (const float*)d_in[1];
    const float* bias = (const float*)d_in[2];
    float* out = (float*)d_out;

    char* ws = (char*)d_ws;
    const size_t partsBytes = (size_t)KSPLIT * NROWS * DIM * sizeof(float);   // 32 MB
    const bool big = ws_size >= partsBytes + (6u << 20);

    __bf16* outb; __bf16* Wt; float* total; float* posv; float* parts = nullptr;
    if (big) {
        parts = (float*)ws;
        outb  = (__bf16*)(ws + partsBytes);                         // 4 MB
        Wt    = (__bf16*)(ws + partsBytes + (4u << 20));            // 1 MB
        total = (float*)(ws + partsBytes + (5u << 20));             // 32 KB
        posv  = (float*)(ws + partsBytes + (5u << 20) + (32u << 10));
    } else {
        outb  = (__bf16*)ws;
        Wt    = (__bf16*)(ws + (4u << 20));
        total = (float*)(ws + (5u << 20));
        posv  = (float*)(ws + (5u << 20) + (32u << 10));
    }

    hipMemsetAsync(total, 0, NROWS * sizeof(float), stream);
    hipMemsetAsync(out, 0, sizeof(float), stream);

    wt_kernel<<<dim3(DIM / 64, EMB / 64), 256, 0, stream>>>(W, Wt);
    if (big) {
        gemm_part_kernel<<<dim3(NROWS / K1_ROWS, KSPLIT), 256, 0, stream>>>(emb, Wt, parts);
        norm_kernel<<<dim3(NROWS / 4), 256, 0, stream>>>(parts, bias, outb);
    } else {
        gemm_norm_kernel<<<dim3(NROWS / K1_ROWS), 256, 0, stream>>>(emb, Wt, bias, outb);
    }
    sim_kernel<<<dim3(NROWS / TILE, NROWS / TILE), 256, 0, stream>>>(outb, total, posv);
    loss_kernel<<<dim3(NROWS / 256), 256, 0, stream>>>(total, posv, out);
}

// Round 3
// 205.654 us; speedup vs baseline: 1.0716x; 1.0099x over previous
//
#include <hip/hip_runtime.h>
#include <math.h>

#define NROWS 8192
#define HALF  4096
#define EMB   2048
#define DIM   256
#define INV_T 10.0f

typedef __bf16 bf16x8v __attribute__((ext_vector_type(8)));
typedef __bf16 bf16x4v __attribute__((ext_vector_type(4)));
typedef float  f32x4   __attribute__((ext_vector_type(4)));

__device__ __forceinline__ void gld_lds16(const void* g, void* l) {
    __builtin_amdgcn_global_load_lds((const __attribute__((address_space(1))) void*)g,
                                     (__attribute__((address_space(3))) void*)l,
                                     16, 0, 0);
}

// ---------- K0: W [2048][256] f32 -> Wt [256][2048] bf16, coalesced tile transpose ----------
__global__ __launch_bounds__(256) void wt_kernel(const float* __restrict__ W,
                                                 __bf16* __restrict__ Wt) {
    __shared__ __bf16 t[64][72];
    const int n0 = blockIdx.x * 64;
    const int k0 = blockIdx.y * 64;
    const int tid = threadIdx.x;
    const int c = tid & 63;
    const int rr = tid >> 6;
#pragma unroll
    for (int it = 0; it < 16; it++) {
        int k = it * 4 + rr;
        t[k][c] = (__bf16)W[(size_t)(k0 + k) * DIM + n0 + c];
    }
    __syncthreads();
#pragma unroll
    for (int it = 0; it < 16; it++) {
        int n = it * 4 + rr;
        Wt[(size_t)(n0 + n) * EMB + k0 + c] = t[c][n];
    }
}

// ---------- K1a: partial GEMM. Tile 64(M) x 256(N) x 512(Kchunk), BK=64, 8 iters ----------
#define KSPLIT  4
#define KCHUNK  (EMB / KSPLIT)   // 512
#define K1_BK   64

__global__ __launch_bounds__(256) void gemm_part_kernel(
    const float* __restrict__ A,      // [8192][2048] f32
    const __bf16* __restrict__ Wt,    // [256][2048] bf16
    float* __restrict__ parts)        // [4][8192][256] f32
{
    // A: fp32, chunked so each row-chunk is 64B: addr(row,k) = [k>>4][row][k&15]
    __shared__ float  a_sh[4][64][16];     // 16 KB
    // B: bf16, two 32-k halves, m97-style 64B rows: addr(col,k) = [k>>5][col][k&31]
    __shared__ __bf16 b_sh[2][DIM][32];    // 32 KB

    const int tid  = threadIdx.x;
    const int wave = tid >> 6, lane = tid & 63;
    const int quad = lane >> 4, l15 = lane & 15;
    const int rowBase = blockIdx.x * 64;
    const int kOff    = blockIdx.y * KCHUNK;
    const int waveCol = wave * 64;         // each wave: all 64 rows x 64 cols

    f32x4 acc[4][4];
    const f32x4 zero = {0.f, 0.f, 0.f, 0.f};
#pragma unroll
    for (int m = 0; m < 4; m++)
#pragma unroll
        for (int n = 0; n < 4; n++) acc[m][n] = zero;

    const int r16  = lane >> 2;          // 0..15 row within 16-group
    const int b4   = (lane & 3);         // 16B sub-chunk

    for (int k0 = 0; k0 < KCHUNK; k0 += K1_BK) {
        __syncthreads();
        // stage A: chunk c = wave, 4 row-groups of 16
#pragma unroll
        for (int j = 0; j < 4; j++) {
            const float* src = A + (size_t)(rowBase + j * 16 + r16) * EMB
                                 + kOff + k0 + wave * 16 + b4 * 4;
            float* dst = (float*)a_sh + ((wave * 64 + j * 16) * 16);
            gld_lds16(src, dst);
        }
        // stage B: 2 halves x 4 col-groups per wave
#pragma unroll
        for (int h = 0; h < 2; h++)
#pragma unroll
            for (int j = 0; j < 4; j++) {
                int g = wave * 4 + j;   // col-group 0..15
                const __bf16* src = Wt + (size_t)(g * 16 + r16) * EMB
                                       + kOff + k0 + h * 32 + b4 * 8;
                __bf16* dst = (__bf16*)b_sh + ((h * DIM + g * 16) * 32);
                gld_lds16(src, dst);
            }
        __syncthreads();
        // compute: 2 k-halves x (4m x 4n)
#pragma unroll
        for (int h = 0; h < 2; h++) {
            bf16x8v af[4], bfv[4];
#pragma unroll
            for (int m = 0; m < 4; m++) {
                int c   = h * 2 + (quad >> 1);
                int off = (quad & 1) * 8;
                f32x4 v0 = *(const f32x4*)&a_sh[c][m * 16 + l15][off];
                f32x4 v1 = *(const f32x4*)&a_sh[c][m * 16 + l15][off + 4];
#pragma unroll
                for (int i = 0; i < 4; i++) { af[m][i] = (__bf16)v0[i]; af[m][4 + i] = (__bf16)v1[i]; }
            }
#pragma unroll
            for (int n = 0; n < 4; n++)
                bfv[n] = *(const bf16x8v*)&b_sh[h][waveCol + n * 16 + l15][quad * 8];
#pragma unroll
            for (int m = 0; m < 4; m++)
#pragma unroll
                for (int n = 0; n < 4; n++)
                    acc[m][n] = __builtin_amdgcn_mfma_f32_16x16x32_bf16(af[m], bfv[n], acc[m][n], 0, 0, 0);
        }
    }

    float* p = parts + (size_t)blockIdx.y * NROWS * DIM;
    // C/D: col = lane&15, row = quad*4 + reg
#pragma unroll
    for (int m = 0; m < 4; m++)
#pragma unroll
        for (int n = 0; n < 4; n++)
#pragma unroll
            for (int r = 0; r < 4; r++)
                p[(size_t)(rowBase + m * 16 + quad * 4 + r) * DIM + waveCol + n * 16 + l15] =
                    acc[m][n][r];
}

// ---------- K1b: sum partials + bias, L2-normalize, emit bf16 X ----------
__global__ __launch_bounds__(256) void norm_kernel(
    const float* __restrict__ parts,
    const float* __restrict__ bias,
    __bf16* __restrict__ outb)
{
    const int tid  = threadIdx.x;
    const int wave = tid >> 6, lane = tid & 63;
    const int row  = blockIdx.x * 4 + wave;

    float4 v = {0.f, 0.f, 0.f, 0.f};
#pragma unroll
    for (int kc = 0; kc < KSPLIT; kc++) {
        float4 pv = *(const float4*)(parts + (size_t)kc * NROWS * DIM + (size_t)row * DIM + lane * 4);
        v.x += pv.x; v.y += pv.y; v.z += pv.z; v.w += pv.w;
    }
    float4 bv = ((const float4*)bias)[lane];
    v.x += bv.x; v.y += bv.y; v.z += bv.z; v.w += bv.w;

    float ss = v.x * v.x + v.y * v.y + v.z * v.z + v.w * v.w;
#pragma unroll
    for (int off = 1; off < 64; off <<= 1) ss += __shfl_xor(ss, off, 64);
    float inv = 1.f / fmaxf(sqrtf(ss), 1e-12f);

    bf16x4v o;
    o[0] = (__bf16)(v.x * inv); o[1] = (__bf16)(v.y * inv);
    o[2] = (__bf16)(v.z * inv); o[3] = (__bf16)(v.w * inv);
    *(bf16x4v*)(outb + (size_t)row * DIM + lane * 4) = o;
}

// ---------- K1 fallback (small ws): single-kernel GEMM+norm ----------
__global__ __launch_bounds__(256) void gemm_norm_kernel(
    const float* __restrict__ A, const __bf16* __restrict__ Wt,
    const float* __restrict__ bias, __bf16* __restrict__ outb)
{
    __shared__ __bf16 a_shF[32][32];
    __shared__ __bf16 b_shF[DIM][32];
    __shared__ float norm2[32];

    const int tid  = threadIdx.x;
    const int wave = tid >> 6, lane = tid & 63;
    const int quad = lane >> 4, l15 = lane & 15;
    const int rowBase = blockIdx.x * 32;
    const int waveRow = (wave >> 1) * 16;
    const int waveCol = (wave & 1) * 128;

    f32x4 acc[8];
    const f32x4 zero = {0.f, 0.f, 0.f, 0.f};
#pragma unroll
    for (int s = 0; s < 8; s++) acc[s] = zero;

    const int ar = tid >> 3;
    const int ac = (tid & 7) * 4;
    const float* aptr = A + (size_t)(rowBase + ar) * EMB + ac;
    float4 a_cur = *(const float4*)aptr;

    for (int k0 = 0; k0 < EMB; k0 += 32) {
        __syncthreads();
        bf16x4v av;
        av[0] = (__bf16)a_cur.x; av[1] = (__bf16)a_cur.y;
        av[2] = (__bf16)a_cur.z; av[3] = (__bf16)a_cur.w;
        *(bf16x4v*)&a_shF[ar][ac] = av;
#pragma unroll
        for (int j = 0; j < 4; j++) {
            int seg = wave * 4 + j;
            int n = seg * 16 + (lane >> 2);
            int kloc = (lane & 3) * 8;
            gld_lds16(Wt + (size_t)n * EMB + k0 + kloc, (__bf16*)b_shF + seg * 512);
        }
        if (k0 + 32 < EMB) a_cur = *(const float4*)(aptr + k0 + 32);
        __syncthreads();
        bf16x8v af = *(const bf16x8v*)&a_shF[waveRow + l15][quad * 8];
#pragma unroll
        for (int s = 0; s < 8; s++) {
            bf16x8v bfv = *(const bf16x8v*)&b_shF[waveCol + s * 16 + l15][quad * 8];
            acc[s] = __builtin_amdgcn_mfma_f32_16x16x32_bf16(af, bfv, acc[s], 0, 0, 0);
        }
    }

    __syncthreads();
    if (tid < 32) norm2[tid] = 0.f;
    __syncthreads();

    float bv[8];
#pragma unroll
    for (int s = 0; s < 8; s++) bv[s] = bias[waveCol + s * 16 + l15];

    float vals[8][4];
    float ss[4] = {0.f, 0.f, 0.f, 0.f};
#pragma unroll
    for (int s = 0; s < 8; s++)
#pragma unroll
        for (int r = 0; r < 4; r++) {
            float v = acc[s][r] + bv[s];
            vals[s][r] = v;
            ss[r] += v * v;
        }
#pragma unroll
    for (int off = 1; off < 16; off <<= 1)
#pragma unroll
        for (int r = 0; r < 4; r++) ss[r] += __shfl_xor(ss[r], off, 64);
    if (l15 == 0)
#pragma unroll
        for (int r = 0; r < 4; r++) atomicAdd(&norm2[waveRow + quad * 4 + r], ss[r]);
    __syncthreads();

    float inv[4];
#pragma unroll
    for (int r = 0; r < 4; r++)
        inv[r] = 1.f / fmaxf(sqrtf(norm2[waveRow + quad * 4 + r]), 1e-12f);

    __bf16* c_sh = &b_shF[0][0];
#pragma unroll
    for (int s = 0; s < 8; s++)
#pragma unroll
        for (int r = 0; r < 4; r++)
            c_sh[(waveRow + quad * 4 + r) * DIM + waveCol + s * 16 + l15] =
                (__bf16)(vals[s][r] * inv[r]);
    __syncthreads();

    const int4* src = (const int4*)c_sh;
    int4* dst = (int4*)(outb + (size_t)rowBase * DIM);
#pragma unroll
    for (int it = 0; it < 4; it++) dst[it * 256 + tid] = src[it * 256 + tid];
}

// ---------- K2: sim = X@X^T, full-K LDS residency, ONE barrier, upper-tri grid ----------
#define TILE 128
#define NTILE (NROWS / TILE)          // 64
#define NBLK  (NTILE * (NTILE + 1) / 2)   // 2080

__global__ __launch_bounds__(256) void sim_kernel(
    const __bf16* __restrict__ X,
    float* __restrict__ total,
    float* __restrict__ posv)
{
    // full-K operand residency: addr(row,k) = [k>>5][row][k&31], 64B rows
    __shared__ __bf16 a_sh[8][TILE][32];   // 64 KB
    __shared__ __bf16 b_sh[8][TILE][32];   // 64 KB
    __shared__ float rowsum[TILE];
    __shared__ float colsum[TILE];

    // linear -> upper-triangle (bx, by)
    const int t = blockIdx.x;
    int bx = (int)((129.0 - sqrt(16641.0 - 8.0 * (double)t)) * 0.5);
    while (64 * (bx + 1) - ((bx + 1) * bx) / 2 <= t) bx++;
    while (64 * bx - (bx * (bx - 1)) / 2 > t) bx--;
    const int by = bx + (t - (64 * bx - (bx * (bx - 1)) / 2));
    const bool diag = (bx == by);

    const int tid  = threadIdx.x;
    const int wave = tid >> 6, lane = tid & 63;
    const int quad = lane >> 4, l15 = lane & 15;
    const int rowBase = bx * TILE;
    const int colBase = by * TILE;
    const int waveRow = (wave >> 1) * 64;
    const int waveCol = (wave & 1) * 64;

    if (tid < TILE) { rowsum[tid] = 0.f; colsum[tid] = 0.f; }

    // stage EVERYTHING: per wave 16 A-issues + 16 B-issues of 1KB each
    const int r16 = lane >> 2;
    const int b4  = lane & 3;
#pragma unroll
    for (int c = 0; c < 8; c++) {
#pragma unroll
        for (int j = 0; j < 2; j++) {
            int rg = wave * 2 + j;   // row-group 0..7
            const __bf16* asrc = X + (size_t)(rowBase + rg * 16 + r16) * DIM + c * 32 + b4 * 8;
            const __bf16* bsrc = X + (size_t)(colBase + rg * 16 + r16) * DIM + c * 32 + b4 * 8;
            gld_lds16(asrc, (__bf16*)a_sh + (c * TILE + rg * 16) * 32);
            gld_lds16(bsrc, (__bf16*)b_sh + (c * TILE + rg * 16) * 32);
        }
    }
    __syncthreads();   // the ONE barrier

    f32x4 acc[4][4];
    const f32x4 zero = {0.f, 0.f, 0.f, 0.f};
#pragma unroll
    for (int m = 0; m < 4; m++)
#pragma unroll
        for (int n = 0; n < 4; n++) acc[m][n] = zero;

#pragma unroll
    for (int ks = 0; ks < 8; ks++) {
        bf16x8v af[4], bfv[4];
#pragma unroll
        for (int m = 0; m < 4; m++)
            af[m] = *(const bf16x8v*)&a_sh[ks][waveRow + m * 16 + l15][quad * 8];
#pragma unroll
        for (int n = 0; n < 4; n++)
            bfv[n] = *(const bf16x8v*)&b_sh[ks][waveCol + n * 16 + l15][quad * 8];
#pragma unroll
        for (int m = 0; m < 4; m++)
#pragma unroll
            for (int n = 0; n < 4; n++)
                acc[m][n] = __builtin_amdgcn_mfma_f32_16x16x32_bf16(af[m], bfv[n], acc[m][n], 0, 0, 0);
    }

    // epilogue: exp, diag mask, partner capture, row+col sums (symmetry)
    float ecol[4] = {0.f, 0.f, 0.f, 0.f};
#pragma unroll
    for (int m = 0; m < 4; m++) {
#pragma unroll
        for (int r = 0; r < 4; r++) {
            int lrow = waveRow + m * 16 + quad * 4 + r;
            int grow = rowBase + lrow;
            float es = 0.f;
#pragma unroll
            for (int n = 0; n < 4; n++) {
                int gcol = colBase + waveCol + n * 16 + l15;
                float s = acc[m][n][r];
                if (gcol - grow == HALF) { posv[grow] = s; posv[gcol] = s; }
                float e = (gcol == grow) ? 0.f : __expf(s * INV_T);
                es += e;
                ecol[n] += e;
            }
#pragma unroll
            for (int off = 1; off < 16; off <<= 1) es += __shfl_xor(es, off, 64);
            if (l15 == 0) atomicAdd(&rowsum[lrow], es);
        }
    }
    if (!diag) {
#pragma unroll
        for (int n = 0; n < 4; n++) {
            ecol[n] += __shfl_xor(ecol[n], 16, 64);
            ecol[n] += __shfl_xor(ecol[n], 32, 64);
        }
        if (quad == 0)
#pragma unroll
            for (int n = 0; n < 4; n++)
                atomicAdd(&colsum[waveCol + n * 16 + l15], ecol[n]);
    }
    __syncthreads();
    if (tid < TILE) {
        atomicAdd(&total[rowBase + tid], rowsum[tid]);
        if (!diag) atomicAdd(&total[colBase + tid], colsum[tid]);
    }
}

// ---------- K3: loss ----------
__global__ __launch_bounds__(256) void loss_kernel(
    const float* __restrict__ total, const float* __restrict__ posv,
    float* __restrict__ out)
{
    __shared__ float red[4];
    const int tid = threadIdx.x;
    const int i = blockIdx.x * 256 + tid;
    float s = posv[i] * INV_T - __logf(total[i]);
#pragma unroll
    for (int off = 1; off < 64; off <<= 1) s += __shfl_xor(s, off, 64);
    if ((tid & 63) == 0) red[tid >> 6] = s;
    __syncthreads();
    if (tid == 0) {
        float v = red[0] + red[1] + red[2] + red[3];
        atomicAdd(out, -v / (float)NROWS);
    }
}

extern "C" void kernel_launch(void* const* d_in, const int* in_sizes, int n_in,
                              void* d_out, int out_size, void* d_ws, size_t ws_size,
                              hipStream_t stream) {
    const float* emb  = (const float*)d_in[0];
    const float* W    = (const float*)d_in[1];
    const float* bias = (const float*)d_in[2];
    float* out = (float*)d_out;

    char* ws = (char*)d_ws;
    const size_t partsBytes = (size_t)KSPLIT * NROWS * DIM * sizeof(float);   // 32 MB
    const bool big = ws_size >= partsBytes + (6u << 20);

    __bf16* outb; __bf16* Wt; float* total; float* posv; float* parts = nullptr;
    if (big) {
        parts = (float*)ws;
        outb  = (__bf16*)(ws + partsBytes);
        Wt    = (__bf16*)(ws + partsBytes + (4u << 20));
        total = (float*)(ws + partsBytes + (5u << 20));
        posv  = (float*)(ws + partsBytes + (5u << 20) + (32u << 10));
    } else {
        outb  = (__bf16*)ws;
        Wt    = (__bf16*)(ws + (4u << 20));
        total = (float*)(ws + (5u << 20));
        posv  = (float*)(ws + (5u << 20) + (32u << 10));
    }

    hipMemsetAsync(total, 0, NROWS * sizeof(float), stream);
    hipMemsetAsync(out, 0, sizeof(float), stream);

    wt_kernel<<<dim3(DIM / 64, EMB / 64), 256, 0, stream>>>(W, Wt);
    if (big) {
        gemm_part_kernel<<<dim3(NROWS / 64, KSPLIT), 256, 0, stream>>>(emb, Wt, parts);
        norm_kernel<<<dim3(NROWS / 4), 256, 0, stream>>>(parts, bias, outb);
    } else {
        gemm_norm_kernel<<<dim3(NROWS / 32), 256, 0, stream>>>(emb, Wt, bias, outb);
    }
    sim_kernel<<<dim3(NBLK), 256, 0, stream>>>(outb, total, posv);
    loss_kernel<<<dim3(NROWS / 256), 256, 0, stream>>>(total, posv, out);
}

// Round 4
// 152.740 us; speedup vs baseline: 1.4429x; 1.3464x over previous
//
#include <hip/hip_runtime.h>
#include <math.h>

#define NROWS 8192
#define HALF  4096
#define EMB   2048
#define DIM   256
#define INV_T 10.0f

typedef __bf16 bf16x8v __attribute__((ext_vector_type(8)));
typedef __bf16 bf16x4v __attribute__((ext_vector_type(4)));
typedef float  f32x4   __attribute__((ext_vector_type(4)));

__device__ __forceinline__ void gld_lds16(const void* g, void* l) {
    __builtin_amdgcn_global_load_lds((const __attribute__((address_space(1))) void*)g,
                                     (__attribute__((address_space(3))) void*)l,
                                     16, 0, 0);
}

// ---------- K0: W [2048][256] f32 -> Wt [256][2048] bf16, coalesced tile transpose ----------
__global__ __launch_bounds__(256) void wt_kernel(const float* __restrict__ W,
                                                 __bf16* __restrict__ Wt) {
    __shared__ __bf16 t[64][72];
    const int n0 = blockIdx.x * 64;
    const int k0 = blockIdx.y * 64;
    const int tid = threadIdx.x;
    const int c = tid & 63;
    const int rr = tid >> 6;
#pragma unroll
    for (int it = 0; it < 16; it++) {
        int k = it * 4 + rr;
        t[k][c] = (__bf16)W[(size_t)(k0 + k) * DIM + n0 + c];
    }
    __syncthreads();
#pragma unroll
    for (int it = 0; it < 16; it++) {
        int n = it * 4 + rr;
        Wt[(size_t)(n0 + n) * EMB + k0 + c] = t[c][n];
    }
}

// ---------- K1a: partial GEMM. Tile 64(M) x 256(N) x 512(Kchunk), BK=64, 8 iters ----------
#define KSPLIT  4
#define KCHUNK  (EMB / KSPLIT)   // 512
#define K1_BK   64

__global__ __launch_bounds__(256) void gemm_part_kernel(
    const float* __restrict__ A,      // [8192][2048] f32
    const __bf16* __restrict__ Wt,    // [256][2048] bf16
    float* __restrict__ parts)        // [4][8192][256] f32
{
    __shared__ float  a_sh[4][64][16];     // 16 KB
    __shared__ __bf16 b_sh[2][DIM][32];    // 32 KB

    const int tid  = threadIdx.x;
    const int wave = tid >> 6, lane = tid & 63;
    const int quad = lane >> 4, l15 = lane & 15;
    const int rowBase = blockIdx.x * 64;
    const int kOff    = blockIdx.y * KCHUNK;
    const int waveCol = wave * 64;

    f32x4 acc[4][4];
    const f32x4 zero = {0.f, 0.f, 0.f, 0.f};
#pragma unroll
    for (int m = 0; m < 4; m++)
#pragma unroll
        for (int n = 0; n < 4; n++) acc[m][n] = zero;

    const int r16  = lane >> 2;
    const int b4   = (lane & 3);

    for (int k0 = 0; k0 < KCHUNK; k0 += K1_BK) {
        __syncthreads();
#pragma unroll
        for (int j = 0; j < 4; j++) {
            const float* src = A + (size_t)(rowBase + j * 16 + r16) * EMB
                                 + kOff + k0 + wave * 16 + b4 * 4;
            float* dst = (float*)a_sh + ((wave * 64 + j * 16) * 16);
            gld_lds16(src, dst);
        }
#pragma unroll
        for (int h = 0; h < 2; h++)
#pragma unroll
            for (int j = 0; j < 4; j++) {
                int g = wave * 4 + j;
                const __bf16* src = Wt + (size_t)(g * 16 + r16) * EMB
                                       + kOff + k0 + h * 32 + b4 * 8;
                __bf16* dst = (__bf16*)b_sh + ((h * DIM + g * 16) * 32);
                gld_lds16(src, dst);
            }
        __syncthreads();
#pragma unroll
        for (int h = 0; h < 2; h++) {
            bf16x8v af[4], bfv[4];
#pragma unroll
            for (int m = 0; m < 4; m++) {
                int c   = h * 2 + (quad >> 1);
                int off = (quad & 1) * 8;
                f32x4 v0 = *(const f32x4*)&a_sh[c][m * 16 + l15][off];
                f32x4 v1 = *(const f32x4*)&a_sh[c][m * 16 + l15][off + 4];
#pragma unroll
                for (int i = 0; i < 4; i++) { af[m][i] = (__bf16)v0[i]; af[m][4 + i] = (__bf16)v1[i]; }
            }
#pragma unroll
            for (int n = 0; n < 4; n++)
                bfv[n] = *(const bf16x8v*)&b_sh[h][waveCol + n * 16 + l15][quad * 8];
#pragma unroll
            for (int m = 0; m < 4; m++)
#pragma unroll
                for (int n = 0; n < 4; n++)
                    acc[m][n] = __builtin_amdgcn_mfma_f32_16x16x32_bf16(af[m], bfv[n], acc[m][n], 0, 0, 0);
        }
    }

    float* p = parts + (size_t)blockIdx.y * NROWS * DIM;
#pragma unroll
    for (int m = 0; m < 4; m++)
#pragma unroll
        for (int n = 0; n < 4; n++)
#pragma unroll
            for (int r = 0; r < 4; r++)
                p[(size_t)(rowBase + m * 16 + quad * 4 + r) * DIM + waveCol + n * 16 + l15] =
                    acc[m][n][r];
}

// ---------- K1b: sum partials + bias, L2-normalize, emit bf16 X ----------
__global__ __launch_bounds__(256) void norm_kernel(
    const float* __restrict__ parts,
    const float* __restrict__ bias,
    __bf16* __restrict__ outb)
{
    const int tid  = threadIdx.x;
    const int wave = tid >> 6, lane = tid & 63;
    const int row  = blockIdx.x * 4 + wave;

    float4 v = {0.f, 0.f, 0.f, 0.f};
#pragma unroll
    for (int kc = 0; kc < KSPLIT; kc++) {
        float4 pv = *(const float4*)(parts + (size_t)kc * NROWS * DIM + (size_t)row * DIM + lane * 4);
        v.x += pv.x; v.y += pv.y; v.z += pv.z; v.w += pv.w;
    }
    float4 bv = ((const float4*)bias)[lane];
    v.x += bv.x; v.y += bv.y; v.z += bv.z; v.w += bv.w;

    float ss = v.x * v.x + v.y * v.y + v.z * v.z + v.w * v.w;
#pragma unroll
    for (int off = 1; off < 64; off <<= 1) ss += __shfl_xor(ss, off, 64);
    float inv = 1.f / fmaxf(sqrtf(ss), 1e-12f);

    bf16x4v o;
    o[0] = (__bf16)(v.x * inv); o[1] = (__bf16)(v.y * inv);
    o[2] = (__bf16)(v.z * inv); o[3] = (__bf16)(v.w * inv);
    *(bf16x4v*)(outb + (size_t)row * DIM + lane * 4) = o;
}

// ---------- K1 fallback (small ws): single-kernel GEMM+norm ----------
__global__ __launch_bounds__(256) void gemm_norm_kernel(
    const float* __restrict__ A, const __bf16* __restrict__ Wt,
    const float* __restrict__ bias, __bf16* __restrict__ outb)
{
    __shared__ __bf16 a_shF[32][32];
    __shared__ __bf16 b_shF[DIM][32];
    __shared__ float norm2[32];

    const int tid  = threadIdx.x;
    const int wave = tid >> 6, lane = tid & 63;
    const int quad = lane >> 4, l15 = lane & 15;
    const int rowBase = blockIdx.x * 32;
    const int waveRow = (wave >> 1) * 16;
    const int waveCol = (wave & 1) * 128;

    f32x4 acc[8];
    const f32x4 zero = {0.f, 0.f, 0.f, 0.f};
#pragma unroll
    for (int s = 0; s < 8; s++) acc[s] = zero;

    const int ar = tid >> 3;
    const int ac = (tid & 7) * 4;
    const float* aptr = A + (size_t)(rowBase + ar) * EMB + ac;
    float4 a_cur = *(const float4*)aptr;

    for (int k0 = 0; k0 < EMB; k0 += 32) {
        __syncthreads();
        bf16x4v av;
        av[0] = (__bf16)a_cur.x; av[1] = (__bf16)a_cur.y;
        av[2] = (__bf16)a_cur.z; av[3] = (__bf16)a_cur.w;
        *(bf16x4v*)&a_shF[ar][ac] = av;
#pragma unroll
        for (int j = 0; j < 4; j++) {
            int seg = wave * 4 + j;
            int n = seg * 16 + (lane >> 2);
            int kloc = (lane & 3) * 8;
            gld_lds16(Wt + (size_t)n * EMB + k0 + kloc, (__bf16*)b_shF + seg * 512);
        }
        if (k0 + 32 < EMB) a_cur = *(const float4*)(aptr + k0 + 32);
        __syncthreads();
        bf16x8v af = *(const bf16x8v*)&a_shF[waveRow + l15][quad * 8];
#pragma unroll
        for (int s = 0; s < 8; s++) {
            bf16x8v bfv = *(const bf16x8v*)&b_shF[waveCol + s * 16 + l15][quad * 8];
            acc[s] = __builtin_amdgcn_mfma_f32_16x16x32_bf16(af, bfv, acc[s], 0, 0, 0);
        }
    }

    __syncthreads();
    if (tid < 32) norm2[tid] = 0.f;
    __syncthreads();

    float bv[8];
#pragma unroll
    for (int s = 0; s < 8; s++) bv[s] = bias[waveCol + s * 16 + l15];

    float vals[8][4];
    float ss[4] = {0.f, 0.f, 0.f, 0.f};
#pragma unroll
    for (int s = 0; s < 8; s++)
#pragma unroll
        for (int r = 0; r < 4; r++) {
            float v = acc[s][r] + bv[s];
            vals[s][r] = v;
            ss[r] += v * v;
        }
#pragma unroll
    for (int off = 1; off < 16; off <<= 1)
#pragma unroll
        for (int r = 0; r < 4; r++) ss[r] += __shfl_xor(ss[r], off, 64);
    if (l15 == 0)
#pragma unroll
        for (int r = 0; r < 4; r++) atomicAdd(&norm2[waveRow + quad * 4 + r], ss[r]);
    __syncthreads();

    float inv[4];
#pragma unroll
    for (int r = 0; r < 4; r++)
        inv[r] = 1.f / fmaxf(sqrtf(norm2[waveRow + quad * 4 + r]), 1e-12f);

    __bf16* c_sh = &b_shF[0][0];
#pragma unroll
    for (int s = 0; s < 8; s++)
#pragma unroll
        for (int r = 0; r < 4; r++)
            c_sh[(waveRow + quad * 4 + r) * DIM + waveCol + s * 16 + l15] =
                (__bf16)(vals[s][r] * inv[r]);
    __syncthreads();

    const int4* src = (const int4*)c_sh;
    int4* dst = (int4*)(outb + (size_t)rowBase * DIM);
#pragma unroll
    for (int it = 0; it < 4; it++) dst[it * 256 + tid] = src[it * 256 + tid];
}

// ---------- K2: sim = X@X^T. BK=64 streaming (32 KB LDS -> 3+ blocks/CU),
//              shuffle-free unique-writer LDS epilogue, upper-tri grid ----------
#define TILE 128
#define NTILE (NROWS / TILE)              // 64
#define NBLK  (NTILE * (NTILE + 1) / 2)   // 2080

__global__ __launch_bounds__(256, 3) void sim_kernel(
    const __bf16* __restrict__ X,
    float* __restrict__ total,
    float* __restrict__ posv)
{
    // 32 KB shared: staging [2 ops][2 kchunks][128 rows][32 k] bf16,
    // later reused as reduce scratch rs[128][2][16] f32 + cs[128][2][4] f32.
    __shared__ __align__(16) char smem[32768];
    __bf16* a_base = (__bf16*)smem;            // [2][128][32]
    __bf16* b_base = (__bf16*)(smem + 16384);  // [2][128][32]
    float*  rs     = (float*)smem;             // [128][2][16] = 16 KB
    float*  cs     = (float*)(smem + 16384);   // [128][2][4]  = 4 KB

    // linear -> upper-triangle (bx, by); row-major so consecutive blocks share bx
    const int t = blockIdx.x;
    int bx = (int)((129.0 - sqrt(16641.0 - 8.0 * (double)t)) * 0.5);
    while (64 * (bx + 1) - ((bx + 1) * bx) / 2 <= t) bx++;
    while (64 * bx - (bx * (bx - 1)) / 2 > t) bx--;
    const int by = bx + (t - (64 * bx - (bx * (bx - 1)) / 2));
    const bool diag = (bx == by);

    const int tid  = threadIdx.x;
    const int wave = tid >> 6, lane = tid & 63;
    const int quad = lane >> 4, l15 = lane & 15;
    const int rowBase = bx * TILE;
    const int colBase = by * TILE;
    const int waveRow = (wave >> 1) * 64;
    const int waveCol = (wave & 1) * 64;

    f32x4 acc[4][4];
    const f32x4 zero = {0.f, 0.f, 0.f, 0.f};
#pragma unroll
    for (int m = 0; m < 4; m++)
#pragma unroll
        for (int n = 0; n < 4; n++) acc[m][n] = zero;

    const int r16 = lane >> 2;
    const int b4  = lane & 3;

    for (int k0 = 0; k0 < DIM; k0 += 64) {
        __syncthreads();
        // stage 64 k-cols of A-rows and B-rows: per wave 4+4 issues of 1 KB
#pragma unroll
        for (int c = 0; c < 2; c++) {
#pragma unroll
            for (int j = 0; j < 2; j++) {
                int rg = wave * 2 + j;   // row-group 0..7
                const __bf16* asrc = X + (size_t)(rowBase + rg * 16 + r16) * DIM + k0 + c * 32 + b4 * 8;
                const __bf16* bsrc = X + (size_t)(colBase + rg * 16 + r16) * DIM + k0 + c * 32 + b4 * 8;
                gld_lds16(asrc, a_base + (c * TILE + rg * 16) * 32);
                gld_lds16(bsrc, b_base + (c * TILE + rg * 16) * 32);
            }
        }
        __syncthreads();
#pragma unroll
        for (int ks = 0; ks < 2; ks++) {
            bf16x8v af[4], bfv[4];
#pragma unroll
            for (int m = 0; m < 4; m++)
                af[m] = *(const bf16x8v*)(a_base + (ks * TILE + waveRow + m * 16 + l15) * 32 + quad * 8);
#pragma unroll
            for (int n = 0; n < 4; n++)
                bfv[n] = *(const bf16x8v*)(b_base + (ks * TILE + waveCol + n * 16 + l15) * 32 + quad * 8);
#pragma unroll
            for (int m = 0; m < 4; m++)
#pragma unroll
                for (int n = 0; n < 4; n++)
                    acc[m][n] = __builtin_amdgcn_mfma_f32_16x16x32_bf16(af[m], bfv[n], acc[m][n], 0, 0, 0);
        }
    }

    // ---- epilogue: per-lane partial sums (no shuffles) ----
    float es[4][4];     // row partial: sum over n, per (m,r)
    float ecol[4];      // col partial: sum over (m,r), per n
#pragma unroll
    for (int n = 0; n < 4; n++) ecol[n] = 0.f;
#pragma unroll
    for (int m = 0; m < 4; m++) {
#pragma unroll
        for (int r = 0; r < 4; r++) {
            int grow = rowBase + waveRow + m * 16 + quad * 4 + r;
            float e_acc = 0.f;
#pragma unroll
            for (int n = 0; n < 4; n++) {
                int gcol = colBase + waveCol + n * 16 + l15;
                float s = acc[m][n][r];
                if (gcol - grow == HALF) { posv[grow] = s; posv[gcol] = s; }
                float e = (gcol == grow) ? 0.f : __expf(s * INV_T);
                e_acc += e;
                ecol[n] += e;
            }
            es[m][r] = e_acc;
        }
    }

    __syncthreads();   // staging LDS is dead; reuse as reduce scratch
    // unique-writer stores: rs[row][waveCol-half][l15], cs[col][waveRow-half][quad]
    const int wc = wave & 1;        // waveCol half
    const int wr = wave >> 1;       // waveRow half
#pragma unroll
    for (int m = 0; m < 4; m++)
#pragma unroll
        for (int r = 0; r < 4; r++) {
            int lrow = waveRow + m * 16 + quad * 4 + r;
            rs[(lrow * 2 + wc) * 16 + l15] = es[m][r];
        }
    if (!diag) {
#pragma unroll
        for (int n = 0; n < 4; n++) {
            int lcol = waveCol + n * 16 + l15;
            cs[(lcol * 2 + wr) * 4 + quad] = ecol[n];
        }
    }
    __syncthreads();

    if (tid < TILE) {
        float rsum = 0.f;
#pragma unroll
        for (int i = 0; i < 32; i++) rsum += rs[tid * 32 + i];
        atomicAdd(&total[rowBase + tid], rsum);
        if (!diag) {
            float csum = 0.f;
#pragma unroll
            for (int i = 0; i < 8; i++) csum += cs[tid * 8 + i];
            atomicAdd(&total[colBase + tid], csum);
        }
    }
}

// ---------- K3: loss ----------
__global__ __launch_bounds__(256) void loss_kernel(
    const float* __restrict__ total, const float* __restrict__ posv,
    float* __restrict__ out)
{
    __shared__ float red[4];
    const int tid = threadIdx.x;
    const int i = blockIdx.x * 256 + tid;
    float s = posv[i] * INV_T - __logf(total[i]);
#pragma unroll
    for (int off = 1; off < 64; off <<= 1) s += __shfl_xor(s, off, 64);
    if ((tid & 63) == 0) red[tid >> 6] = s;
    __syncthreads();
    if (tid == 0) {
        float v = red[0] + red[1] + red[2] + red[3];
        atomicAdd(out, -v / (float)NROWS);
    }
}

extern "C" void kernel_launch(void* const* d_in, const int* in_sizes, int n_in,
                              void* d_out, int out_size, void* d_ws, size_t ws_size,
                              hipStream_t stream) {
    const float* emb  = (const float*)d_in[0];
    const float* W    = (const float*)d_in[1];
    const float* bias = (const float*)d_in[2];
    float* out = (float*)d_out;

    char* ws = (char*)d_ws;
    const size_t partsBytes = (size_t)KSPLIT * NROWS * DIM * sizeof(float);   // 32 MB
    const bool big = ws_size >= partsBytes + (6u << 20);

    __bf16* outb; __bf16* Wt; float* total; float* posv; float* parts = nullptr;
    if (big) {
        parts = (float*)ws;
        outb  = (__bf16*)(ws + partsBytes);
        Wt    = (__bf16*)(ws + partsBytes + (4u << 20));
        total = (float*)(ws + partsBytes + (5u << 20));
        posv  = (float*)(ws + partsBytes + (5u << 20) + (32u << 10));
    } else {
        outb  = (__bf16*)ws;
        Wt    = (__bf16*)(ws + (4u << 20));
        total = (float*)(ws + (5u << 20));
        posv  = (float*)(ws + (5u << 20) + (32u << 10));
    }

    hipMemsetAsync(total, 0, NROWS * sizeof(float), stream);
    hipMemsetAsync(out, 0, sizeof(float), stream);

    wt_kernel<<<dim3(DIM / 64, EMB / 64), 256, 0, stream>>>(W, Wt);
    if (big) {
        gemm_part_kernel<<<dim3(NROWS / 64, KSPLIT), 256, 0, stream>>>(emb, Wt, parts);
        norm_kernel<<<dim3(NROWS / 4), 256, 0, stream>>>(parts, bias, outb);
    } else {
        gemm_norm_kernel<<<dim3(NROWS / 32), 256, 0, stream>>>(emb, Wt, bias, outb);
    }
    sim_kernel<<<dim3(NBLK), 256, 0, stream>>>(outb, total, posv);
    loss_kernel<<<dim3(NROWS / 256), 256, 0, stream>>>(total, posv, out);
}